// Round 14
// baseline (12401.699 us; speedup 1.0000x reference)
//
#include <hip/hip_runtime.h>
#include <hip/hip_bf16.h>
#include <math.h>

// ---------------------------------------------------------------------------
// TrafficSeq2Seq round 14 = round-13 with RMW-free barriers:
//  - global gbarF: release fence + per-WG flag STORE (64B-strided lines),
//    WG0's threads poll in parallel, gen store, acquire fence (r9 semantics,
//    parallel arrivals instead of serialized far-atomics)
//  - local lbarF (encoder): same flag scheme per XCD, no fences; sc0 polls
//    with sc0sc1 safety valve every 64 iters
//  - election counters padded to private cache lines
// Math/structure identical to r13 (passed, absmax 9.77e-4).
// ---------------------------------------------------------------------------

#define NWG 128
#define TPB 256

typedef unsigned short u16;
typedef unsigned int   u32;
typedef short v8s __attribute__((ext_vector_type(8)));
typedef float v4f __attribute__((ext_vector_type(4)));

#define MFMA_(a,b,c) __builtin_amdgcn_mfma_f32_16x16x32_bf16((a),(b),(c),0,0,0)

__device__ __forceinline__ u16 f2bf(float f){
  unsigned u = __builtin_bit_cast(unsigned, f);
  unsigned r = u + 0x7FFFu + ((u >> 16) & 1u);
  return (u16)(r >> 16);
}
__device__ __forceinline__ float bf2f(u16 s){
  unsigned u = ((unsigned)s) << 16;
  return __builtin_bit_cast(float, u);
}
__device__ __forceinline__ void splitstore(u16* ph, u16* pl, float v){
  u16 h = f2bf(v); ph[0] = h; pl[0] = f2bf(v - bf2f(h));
}
__device__ __forceinline__ float sigm(float x){ return 1.f / (1.f + __expf(-x)); }
__device__ __forceinline__ float tanh_f(float x){
  float ax = fabsf(x);
  float t = __expf(-2.f * ax);
  float r = (1.f - t) / (1.f + t);
  return copysignf(r, x);
}

// fragment load: lane holds M[(r0+(lane&15))*ld + k0 + (lane>>4)*8 .. +8)
__device__ __forceinline__ v8s ldfrag(const u16* base, size_t ld, int r0, int k0){
  int lane = threadIdx.x & 63;
  const u16* p = base + (size_t)(r0 + (lane & 15)) * ld + (size_t)(k0 + ((lane >> 4) << 3));
  return *(const v8s*)p;
}

// ---- sc0 (L1-bypass, L2-coherent) batched loads: wait INSIDE block --------
__device__ __forceinline__ void ldx4x4_sc0(v8s&o0,v8s&o1,v8s&o2,v8s&o3,
    const u16*p0,const u16*p1,const u16*p2,const u16*p3){
  asm volatile(
    "global_load_dwordx4 %0, %4, off sc0\n\t"
    "global_load_dwordx4 %1, %5, off sc0\n\t"
    "global_load_dwordx4 %2, %6, off sc0\n\t"
    "global_load_dwordx4 %3, %7, off sc0\n\t"
    "s_waitcnt vmcnt(0)"
    : "=&v"(o0),"=&v"(o1),"=&v"(o2),"=&v"(o3)
    : "v"(p0),"v"(p1),"v"(p2),"v"(p3) : "memory");
}
__device__ __forceinline__ void ldus4_sc0(u32&o0,u32&o1,u32&o2,u32&o3,
    const u16*p0,const u16*p1,const u16*p2,const u16*p3){
  asm volatile(
    "global_load_ushort %0, %4, off sc0\n\t"
    "global_load_ushort %1, %5, off sc0\n\t"
    "global_load_ushort %2, %6, off sc0\n\t"
    "global_load_ushort %3, %7, off sc0\n\t"
    "s_waitcnt vmcnt(0)"
    : "=&v"(o0),"=&v"(o1),"=&v"(o2),"=&v"(o3)
    : "v"(p0),"v"(p1),"v"(p2),"v"(p3) : "memory");
}

// ---- LDS weight slice: [3 gates][16 rows][64 chunks of 8], chunk ^= (row&7)
__device__ __forceinline__ v8s ldfrag_w(const u16* wlds, int gate, int kt){
  int lane = threadIdx.x & 63;
  int rr = lane & 15;
  int ch = (kt*4 + (lane >> 4)) ^ (rr & 7);
  return *(const v8s*)(wlds + (size_t)((gate*16 + rr)*64 + ch) * 8);
}
__device__ void stage_wslice(const float* Wf, u16* wlds, int col0){
  for (int idx = threadIdx.x; idx < 3*16*64; idx += TPB){
    int ch = idx & 63, rr = (idx >> 6) & 15, g = idx >> 10;
    const float* src = Wf + ((size_t)(g*512 + col0 + rr))*512 + ch*8;
    v4f f0 = *(const v4f*)src, f1 = *(const v4f*)(src + 4);
    v8s o;
    #pragma unroll
    for (int j=0;j<4;j++){ o[j] = (short)f2bf(f0[j]); o[4+j] = (short)f2bf(f1[j]); }
    *(v8s*)(wlds + (size_t)((g*16 + rr)*64 + (ch ^ (rr & 7))) * 8) = o;
  }
}
__device__ void stage_wslice_u16(const u16* Wh, const u16* Wl, u16* dh, u16* dl, int col0){
  for (int idx = threadIdx.x; idx < 3*16*64; idx += TPB){
    int ch = idx & 63, rr = (idx >> 6) & 15, g = idx >> 10;
    size_t so = ((size_t)(g*512 + col0 + rr))*512 + ch*8;
    size_t o  = (size_t)((g*16 + rr)*64 + (ch ^ (rr & 7))) * 8;
    *(v8s*)(dh+o) = *(const v8s*)(Wh+so);
    *(v8s*)(dl+o) = *(const v8s*)(Wl+so);
  }
}

struct KArgs {
  const float *x, *target, *eWih_f, *eWhh_f, *ebih, *ebhh;
  const float *dWih0_f, *dWih1_f, *dWhh_f, *dbih, *dbhh;
  const float *aWw_f, *aWb, *aCw_f, *aCb, *o1w_f, *o1b, *o2w_f, *o2b;
  float* out;
  u32 *flags, *genp, *ecnt, *lflags, *lgen;
  u16 *ebf, *ehh;
  u16 *xhi, *h0hi, *h1hi, *encout;
  u16 *dWih0h,*dWih0l,*dWih1h,*dWih1l,*dWhhh,*dWhhl;
  u16 *Wwhh,*Wwhl,*Wwxh,*Wwxl,*Wchh,*Wchl,*Wcxh,*Wcxl;
  u16 *o2wh,*o2wl,*o1Th,*o1Tl,*Wph,*Wpl;
  float *bpr;
  u16 *xth,*xtl;
  float *preW,*preC;
  u16 *dh0h,*dh0l,*dh1h,*dh1l;
  float *logits;
  u16 *wcth,*wctl,*xch,*xcl;
};

// ---- CP-bypass (sc0 sc1) flag ops ------------------------------------------
__device__ __forceinline__ u32 ldcp(const u32* p){
  u32 r;
  asm volatile("global_load_dword %0, %1, off sc0 sc1\n\ts_waitcnt vmcnt(0)"
               : "=&v"(r) : "v"(p) : "memory");
  return r;
}
__device__ __forceinline__ void stcp(u32* p, u32 v){
  asm volatile("global_store_dword %0, %1, off sc0 sc1" :: "v"(p), "v"(v) : "memory");
}
// ---- local (intra-XCD) flag ops: sc0 with periodic sc0sc1 safety valve ----
__device__ __forceinline__ u32 ldl(const u32* p, u32 it){
  u32 r;
  if ((it & 63u) != 0u)
    asm volatile("global_load_dword %0, %1, off sc0\n\ts_waitcnt vmcnt(0)"
                 : "=&v"(r) : "v"(p) : "memory");
  else
    asm volatile("global_load_dword %0, %1, off sc0 sc1\n\ts_waitcnt vmcnt(0)"
                 : "=&v"(r) : "v"(p) : "memory");
  return r;
}
__device__ __forceinline__ void stl(u32* p, u32 v){
  asm volatile("global_store_dword %0, %1, off sc0" :: "v"(p), "v"(v) : "memory");
}

// ---- GLOBAL barrier: RMW-free. release fence -> own-flag store ->
//      WG0 threads poll 64B-strided flags -> gen store -> acquire fence ----
__device__ void gbarF(u32* flags, u32* genp, u32 target){
  __syncthreads();
  __builtin_amdgcn_fence(__ATOMIC_RELEASE, "agent");
  int wg = blockIdx.x, tid = threadIdx.x;
  if (wg == 0){
    if (tid > 0 && tid < NWG){
      while (ldcp(flags + (size_t)tid*16) < target) __builtin_amdgcn_s_sleep(1);
    }
    __syncthreads();
    if (tid == 0) stcp(genp, target);
  } else {
    if (tid == 0){
      stcp(flags + (size_t)wg*16, target);
      while (ldcp(genp) < target) __builtin_amdgcn_s_sleep(1);
    }
  }
  __builtin_amdgcn_fence(__ATOMIC_ACQUIRE, "agent");
  __syncthreads();
}

// ---- LOCAL (intra-XCD) barrier: RMW-free, fence-free ----------------------
__device__ void lbarF(u32* lflags, u32* lgen, int slot, u32 target){
  asm volatile("s_waitcnt vmcnt(0)" ::: "memory");   // my stores at XCD L2
  __syncthreads();                                   // whole WG drained
  int tid = threadIdx.x;
  if (slot == 0){
    if (tid >= 1 && tid < 16){
      u32 it = 0;
      while (ldl(lflags + (size_t)tid*16, ++it) < target) __builtin_amdgcn_s_sleep(1);
    }
    __syncthreads();
    if (tid == 0) stl(lgen, target);
  } else {
    if (tid == 0){
      stl(lflags + (size_t)slot*16, target);
      u32 it = 0;
      while (ldl(lgen, ++it) < target) __builtin_amdgcn_s_sleep(1);
    }
  }
  __syncthreads();
}

// ---- generic 64x16 tile of  C = A @ B^T  (split-bf16 3-pass) --------------
__device__ __forceinline__ v4f tile_xwT(const u16* Ah, const u16* Al, size_t lda, int nks,
                                        const u16* Bh, const u16* Bl, size_t ldb,
                                        int row0, int brow0, v4f* red){
  int tid = threadIdx.x, w = tid >> 6, lane = tid & 63;
  v4f acc[4];
  #pragma unroll
  for (int i=0;i<4;i++) acc[i] = (v4f){0.f,0.f,0.f,0.f};
  for (int ks = w; ks < nks; ks += 4){
    int k0 = ks * 32;
    v8s bh = ldfrag(Bh, ldb, brow0, k0);
    v8s bl = ldfrag(Bl, ldb, brow0, k0);
    #pragma unroll
    for (int rt=0; rt<4; rt++){
      v8s a  = ldfrag(Ah, lda, row0 + rt*16, k0);
      v8s al = ldfrag(Al, lda, row0 + rt*16, k0);
      acc[rt] = MFMA_(a,  bh, acc[rt]);
      acc[rt] = MFMA_(al, bh, acc[rt]);
      acc[rt] = MFMA_(a,  bl, acc[rt]);
    }
  }
  __syncthreads();
  red[(0*4+w)*64+lane]=acc[0]; red[(1*4+w)*64+lane]=acc[1];
  red[(2*4+w)*64+lane]=acc[2]; red[(3*4+w)*64+lane]=acc[3];
  __syncthreads();
  v4f g = red[(w*4+0)*64+lane];
  g += red[(w*4+1)*64+lane]; g += red[(w*4+2)*64+lane]; g += red[(w*4+3)*64+lane];
  return g;
}

// ---- decoder GRU gate tile, Wh (hi+lo) pinned in LDS ----------------------
__device__ __forceinline__ void gru_tile_pin(const u16* Axh, const u16* Axl, size_t ldx, int nkx,
                                             const u16* Ahh, const u16* Ahl,
                                             const u16* Wi,  const u16* Wil, size_t ldwi,
                                             const u16* whp, const u16* wlp,
                                             int row0, int col0, v4f* red, v4f* gate){
  int tid = threadIdx.x, w = tid >> 6, lane = tid & 63;
  v4f acc[4][4];
  #pragma unroll
  for (int i=0;i<4;i++){
    #pragma unroll
    for (int j=0;j<4;j++) acc[i][j] = (v4f){0.f,0.f,0.f,0.f};
  }
  for (int ks = w; ks < nkx; ks += 4){
    int k0 = ks * 32;
    v8s br = ldfrag(Wi, ldwi,        col0, k0);
    v8s bz = ldfrag(Wi, ldwi,  512 + col0, k0);
    v8s bn = ldfrag(Wi, ldwi, 1024 + col0, k0);
    v8s brl = ldfrag(Wil, ldwi, col0, k0);
    v8s bzl = ldfrag(Wil, ldwi, 512+col0, k0);
    v8s bnl = ldfrag(Wil, ldwi, 1024+col0, k0);
    #pragma unroll
    for (int rt=0; rt<4; rt++){
      v8s a  = ldfrag(Axh, ldx, row0 + rt*16, k0);
      v8s al = ldfrag(Axl, ldx, row0 + rt*16, k0);
      acc[rt][0] = MFMA_(a, br, acc[rt][0]); acc[rt][0] = MFMA_(al, br, acc[rt][0]); acc[rt][0] = MFMA_(a, brl, acc[rt][0]);
      acc[rt][1] = MFMA_(a, bz, acc[rt][1]); acc[rt][1] = MFMA_(al, bz, acc[rt][1]); acc[rt][1] = MFMA_(a, bzl, acc[rt][1]);
      acc[rt][2] = MFMA_(a, bn, acc[rt][2]); acc[rt][2] = MFMA_(al, bn, acc[rt][2]); acc[rt][2] = MFMA_(a, bnl, acc[rt][2]);
    }
  }
  for (int ks = w; ks < 16; ks += 4){
    int k0 = ks * 32;
    v8s br  = ldfrag_w(whp, 0, ks), bz  = ldfrag_w(whp, 1, ks), bn  = ldfrag_w(whp, 2, ks);
    v8s brl = ldfrag_w(wlp, 0, ks), bzl = ldfrag_w(wlp, 1, ks), bnl = ldfrag_w(wlp, 2, ks);
    #pragma unroll
    for (int rt=0; rt<4; rt++){
      v8s a  = ldfrag(Ahh, 512, row0 + rt*16, k0);
      v8s al = ldfrag(Ahl, 512, row0 + rt*16, k0);
      acc[rt][0] = MFMA_(a, br, acc[rt][0]); acc[rt][0] = MFMA_(al, br, acc[rt][0]); acc[rt][0] = MFMA_(a, brl, acc[rt][0]);
      acc[rt][1] = MFMA_(a, bz, acc[rt][1]); acc[rt][1] = MFMA_(al, bz, acc[rt][1]); acc[rt][1] = MFMA_(a, bzl, acc[rt][1]);
      acc[rt][3] = MFMA_(a, bn, acc[rt][3]); acc[rt][3] = MFMA_(al, bn, acc[rt][3]); acc[rt][3] = MFMA_(a, bnl, acc[rt][3]);
    }
  }
  #pragma unroll
  for (int ty=0; ty<4; ty++){
    __syncthreads();
    red[(0*4+w)*64+lane]=acc[0][ty]; red[(1*4+w)*64+lane]=acc[1][ty];
    red[(2*4+w)*64+lane]=acc[2][ty]; red[(3*4+w)*64+lane]=acc[3][ty];
    __syncthreads();
    v4f g = red[(w*4+0)*64+lane];
    g += red[(w*4+1)*64+lane]; g += red[(w*4+2)*64+lane]; g += red[(w*4+3)*64+lane];
    gate[ty] = g;
  }
}

__device__ __forceinline__ void gru_combine(const v4f* gate, const float* bih, const float* bhh,
                                            const u16* Hph, const u16* Hpl,
                                            u16* Hnh, u16* Hnl,
                                            int row0, int col0){
  int tid = threadIdx.x, w = tid >> 6, lane = tid & 63;
  int col  = col0 + (lane & 15);
  int rowb = row0 + w*16 + ((lane >> 4) << 2);
  float bir = bih[col], biz = bih[512+col], bin = bih[1024+col];
  float bhr = bhh[col], bhz = bhh[512+col], bhn = bhh[1024+col];
  #pragma unroll
  for (int e=0; e<4; e++){
    int row = rowb + e;
    float r = sigm(gate[0][e] + bir + bhr);
    float z = sigm(gate[1][e] + biz + bhz);
    float n = tanh_f(gate[2][e] + bin + r * (gate[3][e] + bhn));
    float hp = bf2f(Hph[(size_t)row*512 + col]) + bf2f(Hpl[(size_t)row*512 + col]);
    float hv = (1.f - z) * n + z * hp;
    splitstore(&Hnh[(size_t)row*512+col], &Hnl[(size_t)row*512+col], hv);
  }
}

// ---- r12 (fallback) encoder step: weights in LDS, 64-row half --------------
__device__ void enc_step3(const u16* Xb, size_t ldX, const u16* Hp, u16* Hn,
                          u16* encw, int t, const u16* wI, const u16* wH,
                          const float* bih, const float* bhh, int col0, int row0){
  const int tid = threadIdx.x, w = tid>>6, lane = tid&63;
  v4f aR=(v4f){0,0,0,0}, aZ=aR, aNI=aR, aNH=aR;
  const int r0 = row0 + w*16;
  for (int kt=0; kt<16; ++kt){
    int k0 = kt*32;
    v8s bi0=ldfrag_w(wI,0,kt), bi1=ldfrag_w(wI,1,kt), bi2=ldfrag_w(wI,2,kt);
    v8s bh0=ldfrag_w(wH,0,kt), bh1=ldfrag_w(wH,1,kt), bh2=ldfrag_w(wH,2,kt);
    v8s ax = ldfrag(Xb, ldX, r0, k0);
    v8s ah = ldfrag(Hp, 512, r0, k0);
    aR=MFMA_(ax,bi0,aR); aZ=MFMA_(ax,bi1,aZ); aNI=MFMA_(ax,bi2,aNI);
    aR=MFMA_(ah,bh0,aR); aZ=MFMA_(ah,bh1,aZ); aNH=MFMA_(ah,bh2,aNH);
  }
  int col = col0 + (lane&15);
  float bir=bih[col], biz=bih[512+col], bin=bih[1024+col];
  float bhr=bhh[col], bhz=bhh[512+col], bhn=bhh[1024+col];
  int rowb = r0 + ((lane>>4)<<2);
  #pragma unroll
  for (int e=0;e<4;e++){
    int row = rowb + e;
    float r = sigm(aR[e] + bir + bhr);
    float z = sigm(aZ[e] + biz + bhz);
    float n = tanh_f(aNI[e] + bin + r*(aNH[e] + bhn));
    float hp = bf2f(Hp[(size_t)row*512 + col]);
    float hv = (1.f-z)*n + z*hp;
    u16 h16 = f2bf(hv);
    Hn[(size_t)row*512 + col] = h16;
    if (encw) encw[((size_t)row*256 + t)*512 + col] = h16;
  }
}

// ---- balanced-mode encoder step: 16 batches x 32 cols/WG, wave K-split -----
__device__ void enc_stepL(const u16* Xb, size_t ldX, int xsc0,
                          const u16* Hp, u16* Hn, u16* encw, int t,
                          const u16* Wih, const u16* Whh,
                          const float* bih, const float* bhh,
                          int b0, int c0, v4f* red){
  const int tid = threadIdx.x, w = tid>>6, lane = tid&63;
  v4f acc[2][4];
  #pragma unroll
  for (int i=0;i<2;i++)
    #pragma unroll
    for (int j=0;j<4;j++) acc[i][j] = (v4f){0,0,0,0};
  const size_t lo = (size_t)((lane>>4)<<3);
  v8s ax0,ax1,ax2,ax3, ah0,ah1,ah2,ah3;
  {
    const u16* hrow = Hp + (size_t)(b0 + (lane&15))*512 + lo;
    ldx4x4_sc0(ah0,ah1,ah2,ah3,
               hrow + (w*4+0)*32, hrow + (w*4+1)*32, hrow + (w*4+2)*32, hrow + (w*4+3)*32);
  }
  if (xsc0){
    const u16* xrow = Xb + (size_t)(lane&15)*ldX + lo;
    ldx4x4_sc0(ax0,ax1,ax2,ax3,
               xrow + (w*4+0)*32, xrow + (w*4+1)*32, xrow + (w*4+2)*32, xrow + (w*4+3)*32);
  } else {
    ax0 = ldfrag(Xb, ldX, 0, (w*4+0)*32);
    ax1 = ldfrag(Xb, ldX, 0, (w*4+1)*32);
    ax2 = ldfrag(Xb, ldX, 0, (w*4+2)*32);
    ax3 = ldfrag(Xb, ldX, 0, (w*4+3)*32);
  }
  v8s axs[4] = {ax0,ax1,ax2,ax3};
  v8s ahs[4] = {ah0,ah1,ah2,ah3};
  #pragma unroll
  for (int j=0;j<4;j++){
    int k0 = (w*4+j)*32;
    #pragma unroll
    for (int ct=0; ct<2; ct++){
      int cc = c0 + ct*16;
      acc[ct][0] = MFMA_(axs[j], ldfrag(Wih,512,cc,k0),      acc[ct][0]);
      acc[ct][1] = MFMA_(axs[j], ldfrag(Wih,512,512+cc,k0),  acc[ct][1]);
      acc[ct][2] = MFMA_(axs[j], ldfrag(Wih,512,1024+cc,k0), acc[ct][2]);
      acc[ct][0] = MFMA_(ahs[j], ldfrag(Whh,512,cc,k0),      acc[ct][0]);
      acc[ct][1] = MFMA_(ahs[j], ldfrag(Whh,512,512+cc,k0),  acc[ct][1]);
      acc[ct][3] = MFMA_(ahs[j], ldfrag(Whh,512,1024+cc,k0), acc[ct][3]);
    }
  }
  __syncthreads();
  #pragma unroll
  for (int ct=0; ct<2; ct++)
    #pragma unroll
    for (int g=0; g<4; g++)
      red[((ct*4+g)*4 + w)*64 + lane] = acc[ct][g];
  __syncthreads();
  if (w < 2){
    v4f gate[4];
    #pragma unroll
    for (int g=0; g<4; g++){
      v4f s = red[((w*4+g)*4+0)*64+lane];
      s += red[((w*4+g)*4+1)*64+lane];
      s += red[((w*4+g)*4+2)*64+lane];
      s += red[((w*4+g)*4+3)*64+lane];
      gate[g] = s;
    }
    int col = c0 + w*16 + (lane&15);
    int lb  = ((lane>>4)<<2);
    u32 hp0,hp1,hp2,hp3;
    ldus4_sc0(hp0,hp1,hp2,hp3,
              Hp + (size_t)(b0+lb+0)*512 + col, Hp + (size_t)(b0+lb+1)*512 + col,
              Hp + (size_t)(b0+lb+2)*512 + col, Hp + (size_t)(b0+lb+3)*512 + col);
    u32 hpv[4] = {hp0,hp1,hp2,hp3};
    float bir=bih[col], biz=bih[512+col], bin=bih[1024+col];
    float bhr=bhh[col], bhz=bhh[512+col], bhn=bhh[1024+col];
    #pragma unroll
    for (int e=0;e<4;e++){
      int row = b0 + lb + e;
      float r = sigm(gate[0][e] + bir + bhr);
      float z = sigm(gate[1][e] + biz + bhz);
      float n = tanh_f(gate[2][e] + bin + r*(gate[3][e] + bhn));
      float hv = (1.f-z)*n + z*bf2f((u16)hpv[e]);
      u16 h16 = f2bf(hv);
      Hn[(size_t)row*512 + col] = h16;
      if (encw) encw[((size_t)row*256 + t)*512 + col] = h16;
    }
  }
}

__device__ __forceinline__ float blk_max(float v, float* sred){
  #pragma unroll
  for (int off=32; off>0; off>>=1) v = fmaxf(v, __shfl_xor(v, off, 64));
  __syncthreads();
  if ((threadIdx.x & 63) == 0) sred[threadIdx.x >> 6] = v;
  __syncthreads();
  return fmaxf(fmaxf(sred[0], sred[1]), fmaxf(sred[2], sred[3]));
}
__device__ __forceinline__ float blk_sum(float v, float* sred){
  #pragma unroll
  for (int off=32; off>0; off>>=1) v += __shfl_xor(v, off, 64);
  __syncthreads();
  if ((threadIdx.x & 63) == 0) sred[threadIdx.x >> 6] = v;
  __syncthreads();
  return sred[0] + sred[1] + sred[2] + sred[3];
}

#define DECOUT_OFF 0
#define DECHID_OFF 1228800
#define ATTN_OFF   1359872

__global__ void __launch_bounds__(TPB, 1) traffic_kernel(KArgs A){
  __shared__ struct { u16 wI[3*16*64*8]; u16 wH[3*16*64*8]; } WL;  // 96KB
  __shared__ v4f red[8*4*64];   // 32KB
  __shared__ float sred[4];
  __shared__ float awl2[256];
  __shared__ int sh_xcd, sh_slot, sh_bal;
  const int tid = threadIdx.x;
  const int wg  = blockIdx.x;
  const size_t gtid = (size_t)wg * TPB + tid;
  const size_t P = (size_t)NWG * TPB;
  u32 bt = 0;

  // ================= Election: XCD id + slot (startup-only RMW) ============
  {
    u32 xcd;
    asm volatile("s_getreg_b32 %0, hwreg(HW_REG_XCC_ID)" : "=s"(xcd));
    if (tid == 0){
      sh_xcd = (int)(xcd & 7);
      sh_slot = (int)__hip_atomic_fetch_add(A.ecnt + (size_t)(xcd & 7)*16, 1u,
                                            __ATOMIC_RELAXED, __HIP_MEMORY_SCOPE_AGENT);
    }
    __syncthreads();
  }

  // ================= Phase 0: conversion / padding / zeroing ===============
  for (size_t i=gtid; i<128UL*256*512; i+=P) A.xhi[i] = f2bf(A.x[i]);
  for (size_t i=gtid; i<2UL*1536*512; i+=P){ A.ebf[i]=f2bf(A.eWih_f[i]); A.ehh[i]=f2bf(A.eWhh_f[i]); }
  for (size_t i=gtid; i<1536UL*320; i+=P){
    size_t r=i/320, c=i%320;
    float v = (c<300)? A.dWih0_f[r*300+c] : 0.f;
    splitstore(&A.dWih0h[i], &A.dWih0l[i], v);
  }
  for (size_t i=gtid; i<1536UL*512; i+=P) splitstore(&A.dWih1h[i], &A.dWih1l[i], A.dWih1_f[i]);
  for (size_t i=gtid; i<2UL*1536*512; i+=P) splitstore(&A.dWhhh[i], &A.dWhhl[i], A.dWhh_f[i]);
  for (size_t i=gtid; i<256UL*512; i+=P){ size_t r=i>>9, c=i&511; splitstore(&A.Wwhh[i], &A.Wwhl[i], A.aWw_f[r*812+300+c]); }
  for (size_t i=gtid; i<256UL*320; i+=P){ size_t r=i/320, c=i%320; float v=(c<300)? A.aWw_f[r*812+c]:0.f; splitstore(&A.Wwxh[i], &A.Wwxl[i], v); }
  for (size_t i=gtid; i<304UL*512; i+=P){ size_t r=i>>9, c=i&511; float v=(r<300)? A.aCw_f[r*812+300+c]:0.f; splitstore(&A.Wchh[i], &A.Wchl[i], v); }
  for (size_t i=gtid; i<304UL*320; i+=P){ size_t r=i/320, c=i%320; float v=(r<300&&c<300)? A.aCw_f[r*812+c]:0.f; splitstore(&A.Wcxh[i], &A.Wcxl[i], v); }
  for (size_t i=gtid; i<320UL*320; i+=P){ size_t r=i/320, c=i%320; float v=(r<300&&c<300)? A.o2w_f[r*300+c]:0.f; splitstore(&A.o2wh[i], &A.o2wl[i], v); }
  for (size_t i=gtid; i<512UL*320; i+=P){
    size_t j=i/320, k=i%320;
    float v = (k<300)? A.o1w_f[k*512+j] : 0.f;
    splitstore(&A.o1Th[i], &A.o1Tl[i], v);
  }
  for (size_t i=gtid; i<304; i+=P){
    float s = 0.f;
    if (i < 300){
      s = A.o2b[i];
      const float* wrow = A.o2w_f + i*300;
      for (int k=0;k<300;k++) s += wrow[k] * A.o1b[k];
    }
    A.bpr[i] = s;
  }
  for (size_t i=gtid; i<32UL*128*320; i+=P){
    size_t sb=i/320, c=i%320, s2=sb>>7, b=sb&127;
    float v = (c<300)? A.target[(b*33+s2)*300 + c] : 0.f;
    splitstore(&A.xth[i], &A.xtl[i], v);
  }
  for (size_t i=gtid; i<65536; i+=P){ A.h0hi[i]=0; A.h1hi[i]=0; }
  for (size_t i=gtid; i<128UL*320; i+=P){ A.xch[i]=0; A.xcl[i]=0; }
  gbarF(A.flags, A.genp, ++bt);

  // balanced iff every XCD got exactly 16 WGs
  if (tid == 0){
    int ok = 1;
    for (int x2=0; x2<8; x2++)
      ok &= (ldcp(A.ecnt + (size_t)x2*16) == 16u);
    sh_bal = ok;
  }
  __syncthreads();
  const int vwg = sh_bal ? (sh_xcd*16 + sh_slot) : wg;

  // ================= Phase 0b: xt-side attn linears + W' ===================
  for (int tl = vwg; tl < 1024; tl += NWG){
    int rb = tl >> 4, cb = tl & 15;
    int row0 = rb*64, col0 = cb*16;
    v4f g = tile_xwT(A.xth, A.xtl, 320, 10, A.Wwxh, A.Wwxl, 320, row0, col0, red);
    int w = tid>>6, lane = tid&63;
    int col = col0 + (lane&15), rowb = row0 + w*16 + ((lane>>4)<<2);
    #pragma unroll
    for (int e=0;e<4;e++){ int row=rowb+e; A.preW[(size_t)row*256+col] = g[e] + A.aWb[col]; }
  }
  for (int tl = vwg; tl < 1216; tl += NWG){
    int rb = tl / 19, cb = tl % 19;
    int row0 = rb*64, col0 = cb*16;
    v4f g = tile_xwT(A.xth, A.xtl, 320, 10, A.Wcxh, A.Wcxl, 320, row0, col0, red);
    int w = tid>>6, lane = tid&63;
    int col = col0 + (lane&15), rowb = row0 + w*16 + ((lane>>4)<<2);
    #pragma unroll
    for (int e=0;e<4;e++){
      int row=rowb+e;
      float v = (col<300)? (g[e] + A.aCb[col]) : 0.f;
      A.preC[(size_t)row*320+col] = v;
    }
  }
  for (int tl = vwg; tl < 160; tl += NWG){
    int rt = tl >> 5, ct = tl & 31;
    int row0 = rt*64, col0 = ct*16;
    v4f g = tile_xwT(A.o2wh, A.o2wl, 320, 10, A.o1Th, A.o1Tl, 320, row0, col0, red);
    int w = tid>>6, lane = tid&63;
    int col = col0 + (lane&15), rowb = row0 + w*16 + ((lane>>4)<<2);
    #pragma unroll
    for (int e=0;e<4;e++){
      int row = rowb+e;
      if (row < 304) splitstore(&A.Wph[(size_t)row*512+col], &A.Wpl[(size_t)row*512+col], g[e]);
    }
  }
  gbarF(A.flags, A.genp, ++bt);

  // ===================== Encoder ===========================================
  if (sh_bal){
    const int b0 = sh_xcd*16, c0 = sh_slot*32;
    u32* lfl = A.lflags + (size_t)sh_xcd*256;   // 16 lines
    u32* lgn = A.lgen   + (size_t)sh_xcd*16;
    u32 lt = 0;
    for (int t=0; t<256; ++t){
      enc_stepL(A.xhi + (size_t)b0*131072 + (size_t)t*512, 131072, 0,
                A.h0hi + (size_t)t*65536, A.h0hi + (size_t)(t+1)*65536,
                nullptr, 0, A.ebf, A.ehh, A.ebih, A.ebhh, b0, c0, red);
      lbarF(lfl, lgn, sh_slot, ++lt);
    }
    const u16* W1i = A.ebf + (size_t)1536*512;
    const u16* W1h = A.ehh + (size_t)1536*512;
    for (int t=0; t<256; ++t){
      enc_stepL(A.h0hi + (size_t)(t+1)*65536 + (size_t)b0*512, 512, 1,
                A.h1hi + (size_t)(t&1)*65536, A.h1hi + (size_t)((t+1)&1)*65536,
                A.encout, t, W1i, W1h, A.ebih + 1536, A.ebhh + 1536, b0, c0, red);
      lbarF(lfl, lgn, sh_slot, ++lt);
    }
  } else {
    const int grp  = vwg >> 6;
    const int half = (vwg >> 5) & 1;
    const int col0 = (vwg & 31) * 16;
    const int row0 = half * 64;
    stage_wslice(A.eWih_f + (size_t)grp*1536*512, WL.wI, col0);
    stage_wslice(A.eWhh_f + (size_t)grp*1536*512, WL.wH, col0);
    __syncthreads();
    const float* bih = A.ebih + grp*1536;
    const float* bhh = A.ebhh + grp*1536;
    for (int k=0; k<=256; ++k){
      if (grp == 0){
        if (k < 256)
          enc_step3(A.xhi + (size_t)k*512, (size_t)256*512,
                    A.h0hi + (size_t)k*65536, A.h0hi + (size_t)(k+1)*65536,
                    nullptr, 0, WL.wI, WL.wH, bih, bhh, col0, row0);
      } else {
        if (k >= 1){
          int t = k-1;
          enc_step3(A.h0hi + (size_t)k*65536, 512,
                    A.h1hi + (size_t)(t&1)*65536, A.h1hi + (size_t)((t+1)&1)*65536,
                    A.encout, t, WL.wI, WL.wH, bih, bhh, col0, row0);
        }
      }
      gbarF(A.flags, A.genp, ++bt);
    }
  }
  gbarF(A.flags, A.genp, ++bt);   // publish encoder results device-wide

  // ================= Decoder init + pin decoder Whh slices in LDS ==========
  for (size_t i=gtid; i<65536; i+=P){
    A.dh0h[i] = A.h0hi[(size_t)256*65536 + i]; A.dh0l[i] = 0;
    A.dh1h[i] = A.h1hi[i];                     A.dh1l[i] = 0;
  }
  if (vwg < 64){
    int cb = vwg & 31;
    stage_wslice_u16(A.dWhhh, A.dWhhl, WL.wI, WL.wH, cb*16);
  } else {
    int cb = (vwg - 64) & 31;
    stage_wslice_u16(A.dWhhh + (size_t)1536*512, A.dWhhl + (size_t)1536*512, WL.wI, WL.wH, cb*16);
  }
  gbarF(A.flags, A.genp, ++bt);

  // ================= Decoder: 32 steps, 5 barriers/step ====================
  for (int s=0; s<32; s++){
    const u16* h0ph = A.dh0h + (size_t)(s&1)*65536;
    const u16* h0pl = A.dh0l + (size_t)(s&1)*65536;
    u16* h0nh = A.dh0h + (size_t)((s+1)&1)*65536;
    u16* h0nl = A.dh0l + (size_t)((s+1)&1)*65536;
    const u16* h1ph = A.dh1h + (size_t)(s&1)*65536;
    const u16* h1pl = A.dh1l + (size_t)(s&1)*65536;
    u16* h1nh = A.dh1h + (size_t)((s+1)&1)*65536;
    u16* h1nl = A.dh1l + (size_t)((s+1)&1)*65536;

    // Phase A: S1(s) on vwg<32  ||  S8'(s-1) on vwg in [64,102)
    if (vwg < 32){
      int rb = vwg >> 4, cb = vwg & 15;
      int row0 = rb*64, col0 = cb*16;
      v4f g = tile_xwT(h1ph, h1pl, 512, 16, A.Wwhh, A.Wwhl, 512, row0, col0, red);
      const float* pre = A.preW + (size_t)s*128*256;
      int w = tid>>6, lane = tid&63;
      int col = col0 + (lane&15), rowb = row0 + w*16 + ((lane>>4)<<2);
      #pragma unroll
      for (int e=0;e<4;e++){ int row=rowb+e; A.logits[(size_t)row*256+col] = g[e] + pre[(size_t)row*256+col]; }
    } else if (vwg >= 64 && vwg < 102 && s > 0){
      int v2 = vwg - 64;
      int rb = v2 / 19, cb = v2 % 19;
      int row0 = rb*64, col0 = cb*16;
      v4f g = tile_xwT(h1ph, h1pl, 512, 16, A.Wph, A.Wpl, 512, row0, col0, red);
      int w = tid>>6, lane = tid&63;
      int col = col0 + (lane&15), rowb = row0 + w*16 + ((lane>>4)<<2);
      #pragma unroll
      for (int e=0;e<4;e++){
        int row = rowb+e;
        if (col < 300) A.out[DECOUT_OFF + ((size_t)row*32 + (s-1))*300 + col] = g[e] + A.bpr[col];
      }
    }
    gbarF(A.flags, A.genp, ++bt);

    // S2+S3: softmax + context, one batch per WG, wave-chunked t2
    {
      int b = vwg;
      float v = A.logits[(size_t)b*256 + tid];
      float m = blk_max(v, sred);
      float e = __expf(v - m);
      float ssum = blk_sum(e, sred);
      float awv = e / ssum;
      awl2[tid] = awv;
      A.out[ATTN_OFF + ((size_t)b*32 + s)*256 + tid] = awv;
      __syncthreads();
      int w4 = tid >> 6, lane = tid & 63;
      const u16* ebase = A.encout + (size_t)b*256*512 + (size_t)(w4*64)*512 + lane*8;
      float acc8[8];
      #pragma unroll
      for (int q=0;q<8;q++) acc8[q]=0.f;
      for (int j=0;j<64;++j){
        float wv = awl2[w4*64+j];
        v8s ev = *(const v8s*)(ebase + (size_t)j*512);
        #pragma unroll
        for (int q=0;q<8;q++) acc8[q] += wv * bf2f((u16)ev[q]);
      }
      float* rr = (float*)red;
      #pragma unroll
      for (int q=0;q<8;q++) rr[(size_t)tid*8+q] = acc8[q];
      __syncthreads();
      #pragma unroll
      for (int cc=0; cc<2; ++cc){
        int col = tid*2+cc;
        float sum = 0.f;
        #pragma unroll
        for (int w2=0; w2<4; ++w2) sum += rr[(((size_t)w2*64 + (col>>3))<<3) + (col&7)];
        splitstore(&A.wcth[(size_t)b*512+col], &A.wctl[(size_t)b*512+col], sum);
      }
    }
    gbarF(A.flags, A.genp, ++bt);

    // S4: xc = relu(preC[s] + wctx @ Wch^T)
    if (vwg < 38){
      int rb = vwg / 19, cb = vwg % 19;
      int row0 = rb*64, col0 = cb*16;
      v4f g = tile_xwT(A.wcth, A.wctl, 512, 16, A.Wchh, A.Wchl, 512, row0, col0, red);
      const float* pre = A.preC + (size_t)s*128*320;
      int w = tid>>6, lane = tid&63;
      int col = col0 + (lane&15), rowb = row0 + w*16 + ((lane>>4)<<2);
      #pragma unroll
      for (int e=0;e<4;e++){
        int row = rowb+e;
        float v = (col<300)? fmaxf(g[e] + pre[(size_t)row*320+col], 0.f) : 0.f;
        splitstore(&A.xch[(size_t)row*320+col], &A.xcl[(size_t)row*320+col], v);
      }
    }
    gbarF(A.flags, A.genp, ++bt);

    // S5: GRU layer 0 (Whh-L0 pinned; WGs 0-63)
    if (vwg < 64){
      int rb = vwg >> 5, cb = vwg & 31;
      int row0 = rb*64, col0 = cb*16;
      v4f gate[4];
      gru_tile_pin(A.xch, A.xcl, 320, 10, h0ph, h0pl,
                   A.dWih0h, A.dWih0l, 320, WL.wI, WL.wH, row0, col0, red, gate);
      gru_combine(gate, A.dbih, A.dbhh, h0ph, h0pl, h0nh, h0nl, row0, col0);
    }
    gbarF(A.flags, A.genp, ++bt);

    // S6: GRU layer 1 (Whh-L1 pinned; WGs 64-127)
    if (vwg >= 64){
      int v2 = vwg - 64;
      int rb = v2 >> 5, cb = v2 & 31;
      int row0 = rb*64, col0 = cb*16;
      v4f gate[4];
      gru_tile_pin(h0nh, h0nl, 512, 16, h1ph, h1pl,
                   A.dWih1h, A.dWih1l, 512, WL.wI, WL.wH, row0, col0, red, gate);
      gru_combine(gate, A.dbih + 1536, A.dbhh + 1536, h1ph, h1pl, h1nh, h1nl, row0, col0);
    }
    gbarF(A.flags, A.genp, ++bt);
  }

  // tail: S8'(31)
  if (vwg >= 64 && vwg < 102){
    int v2 = vwg - 64;
    int rb = v2 / 19, cb = v2 % 19;
    int row0 = rb*64, col0 = cb*16;
    v4f g = tile_xwT(A.dh1h, A.dh1l, 512, 16, A.Wph, A.Wpl, 512, row0, col0, red);
    int w = tid>>6, lane = tid&63;
    int col = col0 + (lane&15), rowb = row0 + w*16 + ((lane>>4)<<2);
    #pragma unroll
    for (int e=0;e<4;e++){
      int row = rowb+e;
      if (col < 300) A.out[DECOUT_OFF + ((size_t)row*32 + 31)*300 + col] = g[e] + A.bpr[col];
    }
  }

  // ================= dec_hidden output (final h in slot 0) =================
  for (size_t i=gtid; i<65536; i+=P){
    A.out[DECHID_OFF + i]         = bf2f(A.dh0h[i]) + bf2f(A.dh0l[i]);
    A.out[DECHID_OFF + 65536 + i] = bf2f(A.dh1h[i]) + bf2f(A.dh1l[i]);
  }
}

// ===========================================================================
extern "C" void kernel_launch(void* const* d_in, const int* in_sizes, int n_in,
                              void* d_out, int out_size, void* d_ws, size_t ws_size,
                              hipStream_t stream){
  (void)in_sizes; (void)n_in; (void)out_size; (void)ws_size;
  KArgs A;
  A.x       = (const float*)d_in[0];  A.target = (const float*)d_in[1];
  A.eWih_f  = (const float*)d_in[2];  A.eWhh_f = (const float*)d_in[3];
  A.ebih    = (const float*)d_in[4];  A.ebhh   = (const float*)d_in[5];
  A.dWih0_f = (const float*)d_in[6];  A.dWih1_f= (const float*)d_in[7];
  A.dWhh_f  = (const float*)d_in[8];  A.dbih   = (const float*)d_in[9];
  A.dbhh    = (const float*)d_in[10];
  A.aWw_f   = (const float*)d_in[11]; A.aWb    = (const float*)d_in[12];
  A.aCw_f   = (const float*)d_in[13]; A.aCb    = (const float*)d_in[14];
  A.o1w_f   = (const float*)d_in[15]; A.o1b    = (const float*)d_in[16];
  A.o2w_f   = (const float*)d_in[17]; A.o2b    = (const float*)d_in[18];
  A.out = (float*)d_out;

  char* w = (char*)d_ws;
  size_t off = 0;
  auto alloc = [&](size_t bytes)->char*{
    char* p = w + off; off += (bytes + 255) & ~(size_t)255; return p;
  };
  // barrier page: 64B-strided lines, all zeroed each launch
  char* barp = alloc(32768);
  A.flags  = (u32*)barp;                    // flags[wg] @ wg*64B   (8KB)
  A.genp   = (u32*)(barp + 8192);           // 1 line
  A.ecnt   = (u32*)(barp + 8448);           // ecnt[x] @ x*64B      (512B)
  A.lflags = (u32*)(barp + 9472);           // [xcd][slot] @ 64B    (8KB)
  A.lgen   = (u32*)(barp + 17664);          // lgen[x] @ x*64B      (512B)
  A.ebf    = (u16*)alloc(2UL*1536*512*2);
  A.ehh    = (u16*)alloc(2UL*1536*512*2);
  A.xhi    = (u16*)alloc(128UL*256*512*2);
  A.h0hi   = (u16*)alloc(257UL*128*512*2);
  A.h1hi   = (u16*)alloc(2UL*128*512*2);
  A.encout = A.xhi;
  A.dWih0h = (u16*)alloc(1536UL*320*2); A.dWih0l = (u16*)alloc(1536UL*320*2);
  A.dWih1h = (u16*)alloc(1536UL*512*2); A.dWih1l = (u16*)alloc(1536UL*512*2);
  A.dWhhh  = (u16*)alloc(2UL*1536*512*2); A.dWhhl = (u16*)alloc(2UL*1536*512*2);
  A.Wwhh   = (u16*)alloc(256UL*512*2);  A.Wwhl   = (u16*)alloc(256UL*512*2);
  A.Wwxh   = (u16*)alloc(256UL*320*2);  A.Wwxl   = (u16*)alloc(256UL*320*2);
  A.Wchh   = (u16*)alloc(304UL*512*2);  A.Wchl   = (u16*)alloc(304UL*512*2);
  A.Wcxh   = (u16*)alloc(304UL*320*2);  A.Wcxl   = (u16*)alloc(304UL*320*2);
  A.o2wh   = (u16*)alloc(320UL*320*2);  A.o2wl   = (u16*)alloc(320UL*320*2);
  A.o1Th   = (u16*)alloc(512UL*320*2);  A.o1Tl   = (u16*)alloc(512UL*320*2);
  A.Wph    = (u16*)alloc(304UL*512*2);  A.Wpl    = (u16*)alloc(304UL*512*2);
  A.bpr    = (float*)alloc(304UL*4);
  A.xth    = (u16*)alloc(32UL*128*320*2); A.xtl  = (u16*)alloc(32UL*128*320*2);
  A.preW   = (float*)alloc(32UL*128*256*4);
  A.preC   = (float*)alloc(32UL*128*320*4);
  A.dh0h   = (u16*)alloc(2UL*65536*2); A.dh0l = (u16*)alloc(2UL*65536*2);
  A.dh1h   = (u16*)alloc(2UL*65536*2); A.dh1l = (u16*)alloc(2UL*65536*2);
  A.logits = (float*)alloc(128UL*256*4);
  A.wcth   = (u16*)alloc(128UL*512*2); A.wctl = (u16*)alloc(128UL*512*2);
  A.xch    = (u16*)alloc(128UL*320*2); A.xcl  = (u16*)alloc(128UL*320*2);

  hipMemsetAsync(d_ws, 0, 32768, stream);   // reset barrier/election page
  traffic_kernel<<<dim3(NWG), dim3(TPB), 0, stream>>>(A);
}

// Round 15
// 6706.502 us; speedup vs baseline: 1.8492x; 1.8492x over previous
//
#include <hip/hip_runtime.h>
#include <hip/hip_bf16.h>
#include <math.h>

// ---------------------------------------------------------------------------
// TrafficSeq2Seq round 15 = round-12 verbatim (proven empirical optimum,
// 6.69ms, absmax 9.77e-4). r13's XCD-local encoder barrier (+1.1ms) and
// r14's RMW-free flag barrier (+5.7ms) both regressed and are reverted.
//  - 420 global phases; barrier = RELEASE-RMW arrival + sc0sc1-load polls +
//    single agent ACQUIRE fence on exit
//  - XCD-affine work placement via election (vwg = xcd*16+slot)
//  - encoder: 2 layers x 32 colgroups x 2 batch-halves pipelined, weight
//    slices pinned in LDS
//  - decoder: S5/S6 with dWhh col-slices pinned in LDS on disjoint WG sets;
//    S2+S3 fused (1 batch/WG, wave-chunked); S7+S8 fused via W'=o2w@o1w
// ---------------------------------------------------------------------------

#define NWG 128
#define TPB 256

typedef unsigned short u16;
typedef unsigned int   u32;
typedef short v8s __attribute__((ext_vector_type(8)));
typedef float v4f __attribute__((ext_vector_type(4)));

#define MFMA_(a,b,c) __builtin_amdgcn_mfma_f32_16x16x32_bf16((a),(b),(c),0,0,0)

__device__ __forceinline__ u16 f2bf(float f){
  unsigned u = __builtin_bit_cast(unsigned, f);
  unsigned r = u + 0x7FFFu + ((u >> 16) & 1u);
  return (u16)(r >> 16);
}
__device__ __forceinline__ float bf2f(u16 s){
  unsigned u = ((unsigned)s) << 16;
  return __builtin_bit_cast(float, u);
}
__device__ __forceinline__ void splitstore(u16* ph, u16* pl, float v){
  u16 h = f2bf(v); ph[0] = h; pl[0] = f2bf(v - bf2f(h));
}
__device__ __forceinline__ float sigm(float x){ return 1.f / (1.f + __expf(-x)); }
__device__ __forceinline__ float tanh_f(float x){
  float ax = fabsf(x);
  float t = __expf(-2.f * ax);
  float r = (1.f - t) / (1.f + t);
  return copysignf(r, x);
}

// fragment load: lane holds M[(r0+(lane&15))*ld + k0 + (lane>>4)*8 .. +8)
__device__ __forceinline__ v8s ldfrag(const u16* base, size_t ld, int r0, int k0){
  int lane = threadIdx.x & 63;
  const u16* p = base + (size_t)(r0 + (lane & 15)) * ld + (size_t)(k0 + ((lane >> 4) << 3));
  return *(const v8s*)p;
}

// ---- LDS weight slice: [3 gates][16 rows][64 chunks of 8], chunk ^= (row&7)
__device__ __forceinline__ v8s ldfrag_w(const u16* wlds, int gate, int kt){
  int lane = threadIdx.x & 63;
  int rr = lane & 15;
  int ch = (kt*4 + (lane >> 4)) ^ (rr & 7);
  return *(const v8s*)(wlds + (size_t)((gate*16 + rr)*64 + ch) * 8);
}
__device__ void stage_wslice(const float* Wf, u16* wlds, int col0){
  for (int idx = threadIdx.x; idx < 3*16*64; idx += TPB){
    int ch = idx & 63, rr = (idx >> 6) & 15, g = idx >> 10;
    const float* src = Wf + ((size_t)(g*512 + col0 + rr))*512 + ch*8;
    v4f f0 = *(const v4f*)src, f1 = *(const v4f*)(src + 4);
    v8s o;
    #pragma unroll
    for (int j=0;j<4;j++){ o[j] = (short)f2bf(f0[j]); o[4+j] = (short)f2bf(f1[j]); }
    *(v8s*)(wlds + (size_t)((g*16 + rr)*64 + (ch ^ (rr & 7))) * 8) = o;
  }
}
// stage split-bf16 global weight slice (hi+lo) into the same swizzled layout
__device__ void stage_wslice_u16(const u16* Wh, const u16* Wl, u16* dh, u16* dl, int col0){
  for (int idx = threadIdx.x; idx < 3*16*64; idx += TPB){
    int ch = idx & 63, rr = (idx >> 6) & 15, g = idx >> 10;
    size_t so = ((size_t)(g*512 + col0 + rr))*512 + ch*8;
    size_t o  = (size_t)((g*16 + rr)*64 + (ch ^ (rr & 7))) * 8;
    *(v8s*)(dh+o) = *(const v8s*)(Wh+so);
    *(v8s*)(dl+o) = *(const v8s*)(Wl+so);
  }
}

struct KArgs {
  // inputs (f32)
  const float *x, *target, *eWih_f, *eWhh_f, *ebih, *ebhh;
  const float *dWih0_f, *dWih1_f, *dWhh_f, *dbih, *dbhh;
  const float *aWw_f, *aWb, *aCw_f, *aCb, *o1w_f, *o1b, *o2w_f, *o2b;
  float* out;
  // barrier page
  u32 *flags, *genp, *ecnt;
  // bf16 weights / activations in ws
  u16 *xhi, *h0hi, *h1hi, *encout;
  u16 *dWih0h,*dWih0l,*dWih1h,*dWih1l,*dWhhh,*dWhhl;
  u16 *Wwhh,*Wwhl,*Wwxh,*Wwxl,*Wchh,*Wchl,*Wcxh,*Wcxl;
  u16 *o2wh,*o2wl,*o1Th,*o1Tl,*Wph,*Wpl;
  float *bpr;
  u16 *xth,*xtl;
  float *preW,*preC;
  u16 *dh0h,*dh0l,*dh1h,*dh1l;
  float *logits;
  u16 *wcth,*wctl,*xch,*xcl;
};

// ---- CP-bypass flag load: reads coherence-point value, no RMW, no inv -----
__device__ __forceinline__ u32 ldcp(const u32* p){
  u32 r;
  asm volatile("global_load_dword %0, %1, off sc0 sc1\n\ts_waitcnt vmcnt(0)"
               : "=&v"(r) : "v"(p) : "memory");
  return r;
}

// ---- grid barrier: RELEASE RMW arrival, sc-load polls, ACQUIRE fence exit --
__device__ void gbar(u32* flags, u32* genp, u32 target){
  __syncthreads();
  int wg = blockIdx.x, tid = threadIdx.x;
  if (wg == 0){
    if (tid > 0 && tid < NWG){
      while (ldcp(&flags[tid]) < target) __builtin_amdgcn_s_sleep(1);
    }
    __syncthreads();
    if (tid == 0)
      __hip_atomic_fetch_add(genp, 1u, __ATOMIC_RELEASE, __HIP_MEMORY_SCOPE_AGENT);
  } else {
    if (tid == 0){
      __hip_atomic_fetch_add(&flags[wg], 1u, __ATOMIC_RELEASE, __HIP_MEMORY_SCOPE_AGENT);
      while (ldcp(genp) < target) __builtin_amdgcn_s_sleep(1);
    }
  }
  __builtin_amdgcn_fence(__ATOMIC_ACQUIRE, "agent");
  __syncthreads();
}

// ---- generic 64x16 tile of  C = A @ B^T  (split-bf16 3-pass) --------------
__device__ __forceinline__ v4f tile_xwT(const u16* Ah, const u16* Al, size_t lda, int nks,
                                        const u16* Bh, const u16* Bl, size_t ldb,
                                        int row0, int brow0, v4f* red){
  int tid = threadIdx.x, w = tid >> 6, lane = tid & 63;
  v4f acc[4];
  #pragma unroll
  for (int i=0;i<4;i++) acc[i] = (v4f){0.f,0.f,0.f,0.f};
  for (int ks = w; ks < nks; ks += 4){
    int k0 = ks * 32;
    v8s bh = ldfrag(Bh, ldb, brow0, k0);
    v8s bl = ldfrag(Bl, ldb, brow0, k0);
    #pragma unroll
    for (int rt=0; rt<4; rt++){
      v8s a  = ldfrag(Ah, lda, row0 + rt*16, k0);
      v8s al = ldfrag(Al, lda, row0 + rt*16, k0);
      acc[rt] = MFMA_(a,  bh, acc[rt]);
      acc[rt] = MFMA_(al, bh, acc[rt]);
      acc[rt] = MFMA_(a,  bl, acc[rt]);
    }
  }
  __syncthreads();
  red[(0*4+w)*64+lane]=acc[0]; red[(1*4+w)*64+lane]=acc[1];
  red[(2*4+w)*64+lane]=acc[2]; red[(3*4+w)*64+lane]=acc[3];
  __syncthreads();
  v4f g = red[(w*4+0)*64+lane];
  g += red[(w*4+1)*64+lane]; g += red[(w*4+2)*64+lane]; g += red[(w*4+3)*64+lane];
  return g;
}

// ---- decoder GRU gate tile, Wh (hi+lo) PINNED in LDS ----------------------
__device__ __forceinline__ void gru_tile_pin(const u16* Axh, const u16* Axl, size_t ldx, int nkx,
                                             const u16* Ahh, const u16* Ahl,
                                             const u16* Wi,  const u16* Wil, size_t ldwi,
                                             const u16* whp, const u16* wlp,
                                             int row0, int col0, v4f* red, v4f* gate){
  int tid = threadIdx.x, w = tid >> 6, lane = tid & 63;
  v4f acc[4][4];
  #pragma unroll
  for (int i=0;i<4;i++){
    #pragma unroll
    for (int j=0;j<4;j++) acc[i][j] = (v4f){0.f,0.f,0.f,0.f};
  }
  for (int ks = w; ks < nkx; ks += 4){
    int k0 = ks * 32;
    v8s br = ldfrag(Wi, ldwi,        col0, k0);
    v8s bz = ldfrag(Wi, ldwi,  512 + col0, k0);
    v8s bn = ldfrag(Wi, ldwi, 1024 + col0, k0);
    v8s brl = ldfrag(Wil, ldwi, col0, k0);
    v8s bzl = ldfrag(Wil, ldwi, 512+col0, k0);
    v8s bnl = ldfrag(Wil, ldwi, 1024+col0, k0);
    #pragma unroll
    for (int rt=0; rt<4; rt++){
      v8s a  = ldfrag(Axh, ldx, row0 + rt*16, k0);
      v8s al = ldfrag(Axl, ldx, row0 + rt*16, k0);
      acc[rt][0] = MFMA_(a, br, acc[rt][0]); acc[rt][0] = MFMA_(al, br, acc[rt][0]); acc[rt][0] = MFMA_(a, brl, acc[rt][0]);
      acc[rt][1] = MFMA_(a, bz, acc[rt][1]); acc[rt][1] = MFMA_(al, bz, acc[rt][1]); acc[rt][1] = MFMA_(a, bzl, acc[rt][1]);
      acc[rt][2] = MFMA_(a, bn, acc[rt][2]); acc[rt][2] = MFMA_(al, bn, acc[rt][2]); acc[rt][2] = MFMA_(a, bnl, acc[rt][2]);
    }
  }
  for (int ks = w; ks < 16; ks += 4){
    int k0 = ks * 32;
    v8s br  = ldfrag_w(whp, 0, ks), bz  = ldfrag_w(whp, 1, ks), bn  = ldfrag_w(whp, 2, ks);
    v8s brl = ldfrag_w(wlp, 0, ks), bzl = ldfrag_w(wlp, 1, ks), bnl = ldfrag_w(wlp, 2, ks);
    #pragma unroll
    for (int rt=0; rt<4; rt++){
      v8s a  = ldfrag(Ahh, 512, row0 + rt*16, k0);
      v8s al = ldfrag(Ahl, 512, row0 + rt*16, k0);
      acc[rt][0] = MFMA_(a, br, acc[rt][0]); acc[rt][0] = MFMA_(al, br, acc[rt][0]); acc[rt][0] = MFMA_(a, brl, acc[rt][0]);
      acc[rt][1] = MFMA_(a, bz, acc[rt][1]); acc[rt][1] = MFMA_(al, bz, acc[rt][1]); acc[rt][1] = MFMA_(a, bzl, acc[rt][1]);
      acc[rt][3] = MFMA_(a, bn, acc[rt][3]); acc[rt][3] = MFMA_(al, bn, acc[rt][3]); acc[rt][3] = MFMA_(a, bnl, acc[rt][3]);
    }
  }
  #pragma unroll
  for (int ty=0; ty<4; ty++){
    __syncthreads();
    red[(0*4+w)*64+lane]=acc[0][ty]; red[(1*4+w)*64+lane]=acc[1][ty];
    red[(2*4+w)*64+lane]=acc[2][ty]; red[(3*4+w)*64+lane]=acc[3][ty];
    __syncthreads();
    v4f g = red[(w*4+0)*64+lane];
    g += red[(w*4+1)*64+lane]; g += red[(w*4+2)*64+lane]; g += red[(w*4+3)*64+lane];
    gate[ty] = g;
  }
}

__device__ __forceinline__ void gru_combine(const v4f* gate, const float* bih, const float* bhh,
                                            const u16* Hph, const u16* Hpl,
                                            u16* Hnh, u16* Hnl,
                                            int row0, int col0){
  int tid = threadIdx.x, w = tid >> 6, lane = tid & 63;
  int col  = col0 + (lane & 15);
  int rowb = row0 + w*16 + ((lane >> 4) << 2);
  float bir = bih[col], biz = bih[512+col], bin = bih[1024+col];
  float bhr = bhh[col], bhz = bhh[512+col], bhn = bhh[1024+col];
  #pragma unroll
  for (int e=0; e<4; e++){
    int row = rowb + e;
    float r = sigm(gate[0][e] + bir + bhr);
    float z = sigm(gate[1][e] + biz + bhz);
    float n = tanh_f(gate[2][e] + bin + r * (gate[3][e] + bhn));
    float hp = bf2f(Hph[(size_t)row*512 + col]) + bf2f(Hpl[(size_t)row*512 + col]);
    float hv = (1.f - z) * n + z * hp;
    splitstore(&Hnh[(size_t)row*512+col], &Hnl[(size_t)row*512+col], hv);
  }
}

// ---- encoder step, 64-row half: wave w owns rows row0 + w*16 .. +16 --------
__device__ void enc_step3(const u16* Xb, size_t ldX, const u16* Hp, u16* Hn,
                          u16* encw, int t, const u16* wI, const u16* wH,
                          const float* bih, const float* bhh, int col0, int row0){
  const int tid = threadIdx.x, w = tid>>6, lane = tid&63;
  v4f aR=(v4f){0,0,0,0}, aZ=aR, aNI=aR, aNH=aR;
  const int r0 = row0 + w*16;
  for (int kt=0; kt<16; ++kt){
    int k0 = kt*32;
    v8s bi0=ldfrag_w(wI,0,kt), bi1=ldfrag_w(wI,1,kt), bi2=ldfrag_w(wI,2,kt);
    v8s bh0=ldfrag_w(wH,0,kt), bh1=ldfrag_w(wH,1,kt), bh2=ldfrag_w(wH,2,kt);
    v8s ax = ldfrag(Xb, ldX, r0, k0);
    v8s ah = ldfrag(Hp, 512, r0, k0);
    aR=MFMA_(ax,bi0,aR); aZ=MFMA_(ax,bi1,aZ); aNI=MFMA_(ax,bi2,aNI);
    aR=MFMA_(ah,bh0,aR); aZ=MFMA_(ah,bh1,aZ); aNH=MFMA_(ah,bh2,aNH);
  }
  int col = col0 + (lane&15);
  float bir=bih[col], biz=bih[512+col], bin=bih[1024+col];
  float bhr=bhh[col], bhz=bhh[512+col], bhn=bhh[1024+col];
  int rowb = r0 + ((lane>>4)<<2);
  #pragma unroll
  for (int e=0;e<4;e++){
    int row = rowb + e;
    float r = sigm(aR[e] + bir + bhr);
    float z = sigm(aZ[e] + biz + bhz);
    float n = tanh_f(aNI[e] + bin + r*(aNH[e] + bhn));
    float hp = bf2f(Hp[(size_t)row*512 + col]);
    float hv = (1.f-z)*n + z*hp;
    u16 h16 = f2bf(hv);
    Hn[(size_t)row*512 + col] = h16;
    if (encw) encw[((size_t)row*256 + t)*512 + col] = h16;
  }
}

__device__ __forceinline__ float blk_max(float v, float* sred){
  #pragma unroll
  for (int off=32; off>0; off>>=1) v = fmaxf(v, __shfl_xor(v, off, 64));
  __syncthreads();
  if ((threadIdx.x & 63) == 0) sred[threadIdx.x >> 6] = v;
  __syncthreads();
  return fmaxf(fmaxf(sred[0], sred[1]), fmaxf(sred[2], sred[3]));
}
__device__ __forceinline__ float blk_sum(float v, float* sred){
  #pragma unroll
  for (int off=32; off>0; off>>=1) v += __shfl_xor(v, off, 64);
  __syncthreads();
  if ((threadIdx.x & 63) == 0) sred[threadIdx.x >> 6] = v;
  __syncthreads();
  return sred[0] + sred[1] + sred[2] + sred[3];
}

#define DECOUT_OFF 0
#define DECHID_OFF 1228800      // 128*32*300
#define ATTN_OFF   1359872      // + 2*128*512

__global__ void __launch_bounds__(TPB, 1) traffic_kernel(KArgs A){
  __shared__ struct { u16 wI[3*16*64*8]; u16 wH[3*16*64*8]; } WL;  // 96KB
  __shared__ v4f red[4*4*64];   // 16KB reduce scratch
  __shared__ float sred[4];
  __shared__ float awl2[256];   // 1KB (decoder softmax row)
  __shared__ int sh_xcd, sh_slot, sh_bal;
  const int tid = threadIdx.x;
  const int wg  = blockIdx.x;
  const size_t gtid = (size_t)wg * TPB + tid;
  const size_t P = (size_t)NWG * TPB;
  u32 bt = 0;

  // ================= Election: XCD id + slot ===============================
  {
    u32 xcd;
    asm volatile("s_getreg_b32 %0, hwreg(HW_REG_XCC_ID)" : "=s"(xcd));
    if (tid == 0){
      sh_xcd = (int)(xcd & 7);
      sh_slot = (int)__hip_atomic_fetch_add(&A.ecnt[sh_xcd], 1u, __ATOMIC_RELAXED, __HIP_MEMORY_SCOPE_AGENT);
    }
    __syncthreads();
  }

  // ================= Phase 0: conversion / padding / zeroing ===============
  for (size_t i=gtid; i<128UL*256*512; i+=P) A.xhi[i] = f2bf(A.x[i]);
  for (size_t i=gtid; i<1536UL*320; i+=P){
    size_t r=i/320, c=i%320;
    float v = (c<300)? A.dWih0_f[r*300+c] : 0.f;
    splitstore(&A.dWih0h[i], &A.dWih0l[i], v);
  }
  for (size_t i=gtid; i<1536UL*512; i+=P) splitstore(&A.dWih1h[i], &A.dWih1l[i], A.dWih1_f[i]);
  for (size_t i=gtid; i<2UL*1536*512; i+=P) splitstore(&A.dWhhh[i], &A.dWhhl[i], A.dWhh_f[i]);
  for (size_t i=gtid; i<256UL*512; i+=P){ size_t r=i>>9, c=i&511; splitstore(&A.Wwhh[i], &A.Wwhl[i], A.aWw_f[r*812+300+c]); }
  for (size_t i=gtid; i<256UL*320; i+=P){ size_t r=i/320, c=i%320; float v=(c<300)? A.aWw_f[r*812+c]:0.f; splitstore(&A.Wwxh[i], &A.Wwxl[i], v); }
  for (size_t i=gtid; i<304UL*512; i+=P){ size_t r=i>>9, c=i&511; float v=(r<300)? A.aCw_f[r*812+300+c]:0.f; splitstore(&A.Wchh[i], &A.Wchl[i], v); }
  for (size_t i=gtid; i<304UL*320; i+=P){ size_t r=i/320, c=i%320; float v=(r<300&&c<300)? A.aCw_f[r*812+c]:0.f; splitstore(&A.Wcxh[i], &A.Wcxl[i], v); }
  for (size_t i=gtid; i<320UL*320; i+=P){ size_t r=i/320, c=i%320; float v=(r<300&&c<300)? A.o2w_f[r*300+c]:0.f; splitstore(&A.o2wh[i], &A.o2wl[i], v); }
  for (size_t i=gtid; i<512UL*320; i+=P){
    size_t j=i/320, k=i%320;
    float v = (k<300)? A.o1w_f[k*512+j] : 0.f;
    splitstore(&A.o1Th[i], &A.o1Tl[i], v);
  }
  for (size_t i=gtid; i<304; i+=P){
    float s = 0.f;
    if (i < 300){
      s = A.o2b[i];
      const float* wrow = A.o2w_f + i*300;
      for (int k=0;k<300;k++) s += wrow[k] * A.o1b[k];
    }
    A.bpr[i] = s;
  }
  for (size_t i=gtid; i<32UL*128*320; i+=P){
    size_t sb=i/320, c=i%320, s2=sb>>7, b=sb&127;
    float v = (c<300)? A.target[(b*33+s2)*300 + c] : 0.f;
    splitstore(&A.xth[i], &A.xtl[i], v);
  }
  for (size_t i=gtid; i<65536; i+=P){ A.h0hi[i]=0; A.h1hi[i]=0; }
  for (size_t i=gtid; i<128UL*320; i+=P){ A.xch[i]=0; A.xcl[i]=0; }
  gbar(A.flags, A.genp, ++bt);

  // election result (final after B1); identity fallback if not 16/XCD
  if (tid == 0){
    int ok = 1;
    for (int x2=0; x2<8; x2++)
      ok &= (__hip_atomic_fetch_add(&A.ecnt[x2], 0u, __ATOMIC_RELAXED, __HIP_MEMORY_SCOPE_AGENT) == 16u);
    sh_bal = ok;
  }
  __syncthreads();
  const int vwg = sh_bal ? (sh_xcd*16 + sh_slot) : wg;

  // ================= Phase 0b: xt-side attn linears + W' ===================
  for (int tl = vwg; tl < 1024; tl += NWG){        // preW: (32*128) x 256
    int rb = tl >> 4, cb = tl & 15;
    int row0 = rb*64, col0 = cb*16;
    v4f g = tile_xwT(A.xth, A.xtl, 320, 10, A.Wwxh, A.Wwxl, 320, row0, col0, red);
    int w = tid>>6, lane = tid&63;
    int col = col0 + (lane&15), rowb = row0 + w*16 + ((lane>>4)<<2);
    #pragma unroll
    for (int e=0;e<4;e++){ int row=rowb+e; A.preW[(size_t)row*256+col] = g[e] + A.aWb[col]; }
  }
  for (int tl = vwg; tl < 1216; tl += NWG){        // preC: (32*128) x 304
    int rb = tl / 19, cb = tl % 19;
    int row0 = rb*64, col0 = cb*16;
    v4f g = tile_xwT(A.xth, A.xtl, 320, 10, A.Wcxh, A.Wcxl, 320, row0, col0, red);
    int w = tid>>6, lane = tid&63;
    int col = col0 + (lane&15), rowb = row0 + w*16 + ((lane>>4)<<2);
    #pragma unroll
    for (int e=0;e<4;e++){
      int row=rowb+e;
      float v = (col<300)? (g[e] + A.aCb[col]) : 0.f;
      A.preC[(size_t)row*320+col] = v;
    }
  }
  for (int tl = vwg; tl < 160; tl += NWG){         // W' = o2w @ o1w  (320pad x 512)
    int rt = tl >> 5, ct = tl & 31;
    int row0 = rt*64, col0 = ct*16;
    v4f g = tile_xwT(A.o2wh, A.o2wl, 320, 10, A.o1Th, A.o1Tl, 320, row0, col0, red);
    int w = tid>>6, lane = tid&63;
    int col = col0 + (lane&15), rowb = row0 + w*16 + ((lane>>4)<<2);
    #pragma unroll
    for (int e=0;e<4;e++){
      int row = rowb+e;
      if (row < 304) splitstore(&A.Wph[(size_t)row*512+col], &A.Wpl[(size_t)row*512+col], g[e]);
    }
  }
  gbar(A.flags, A.genp, ++bt);

  // ===== Encoder: XCD-affine classes (layer, batch-half, col), pipelined ===
  {
    const int grp  = vwg >> 6;                 // layer
    const int half = (vwg >> 5) & 1;           // batch half
    const int col0 = (vwg & 31) * 16;
    const int row0 = half * 64;
    stage_wslice(A.eWih_f + (size_t)grp*1536*512, WL.wI, col0);
    stage_wslice(A.eWhh_f + (size_t)grp*1536*512, WL.wH, col0);
    __syncthreads();
    const float* bih = A.ebih + grp*1536;
    const float* bhh = A.ebhh + grp*1536;
    for (int k=0; k<=256; ++k){
      if (grp == 0){
        if (k < 256)
          enc_step3(A.xhi + (size_t)k*512, (size_t)256*512,
                    A.h0hi + (size_t)k*65536, A.h0hi + (size_t)(k+1)*65536,
                    nullptr, 0, WL.wI, WL.wH, bih, bhh, col0, row0);
      } else {
        if (k >= 1){
          int t = k-1;
          enc_step3(A.h0hi + (size_t)k*65536, 512,
                    A.h1hi + (size_t)(t&1)*65536, A.h1hi + (size_t)((t+1)&1)*65536,
                    A.encout, t, WL.wI, WL.wH, bih, bhh, col0, row0);
        }
      }
      gbar(A.flags, A.genp, ++bt);
    }
  }

  // ================= Decoder init + pin decoder Whh slices in LDS ==========
  for (size_t i=gtid; i<65536; i+=P){
    A.dh0h[i] = A.h0hi[(size_t)256*65536 + i]; A.dh0l[i] = 0;
    A.dh1h[i] = A.h1hi[i];                     A.dh1l[i] = 0;   // layer1 final in buf 0
  }
  if (vwg < 64){
    int cb = vwg & 31;
    stage_wslice_u16(A.dWhhh, A.dWhhl, WL.wI, WL.wH, cb*16);
  } else {
    int cb = (vwg - 64) & 31;
    stage_wslice_u16(A.dWhhh + (size_t)1536*512, A.dWhhl + (size_t)1536*512, WL.wI, WL.wH, cb*16);
  }
  gbar(A.flags, A.genp, ++bt);

  // ================= Decoder: 32 steps, 5 barriers/step ====================
  for (int s=0; s<32; s++){
    const u16* h0ph = A.dh0h + (size_t)(s&1)*65536;
    const u16* h0pl = A.dh0l + (size_t)(s&1)*65536;
    u16* h0nh = A.dh0h + (size_t)((s+1)&1)*65536;
    u16* h0nl = A.dh0l + (size_t)((s+1)&1)*65536;
    const u16* h1ph = A.dh1h + (size_t)(s&1)*65536;
    const u16* h1pl = A.dh1l + (size_t)(s&1)*65536;
    u16* h1nh = A.dh1h + (size_t)((s+1)&1)*65536;
    u16* h1nl = A.dh1l + (size_t)((s+1)&1)*65536;

    // S1: logits = preW[s] + h1 @ Wwh^T      (128 x 256)
    if (vwg < 32){
      int rb = vwg >> 4, cb = vwg & 15;
      int row0 = rb*64, col0 = cb*16;
      v4f g = tile_xwT(h1ph, h1pl, 512, 16, A.Wwhh, A.Wwhl, 512, row0, col0, red);
      const float* pre = A.preW + (size_t)s*128*256;
      int w = tid>>6, lane = tid&63;
      int col = col0 + (lane&15), rowb = row0 + w*16 + ((lane>>4)<<2);
      #pragma unroll
      for (int e=0;e<4;e++){ int row=rowb+e; A.logits[(size_t)row*256+col] = g[e] + pre[(size_t)row*256+col]; }
    }
    gbar(A.flags, A.genp, ++bt);

    // S2+S3: softmax + context, ONE batch per WG, wave-chunked t2
    {
      int b = vwg;
      float v = A.logits[(size_t)b*256 + tid];
      float m = blk_max(v, sred);
      float e = __expf(v - m);
      float ssum = blk_sum(e, sred);
      float awv = e / ssum;
      awl2[tid] = awv;
      A.out[ATTN_OFF + ((size_t)b*32 + s)*256 + tid] = awv;
      __syncthreads();
      int w4 = tid >> 6, lane = tid & 63;
      const u16* ebase = A.encout + (size_t)b*256*512 + (size_t)(w4*64)*512 + lane*8;
      float acc8[8];
      #pragma unroll
      for (int q=0;q<8;q++) acc8[q]=0.f;
      for (int j=0;j<64;++j){
        float wv = awl2[w4*64+j];
        v8s ev = *(const v8s*)(ebase + (size_t)j*512);
        #pragma unroll
        for (int q=0;q<8;q++) acc8[q] += wv * bf2f((u16)ev[q]);
      }
      float* rr = (float*)red;
      #pragma unroll
      for (int q=0;q<8;q++) rr[(size_t)tid*8+q] = acc8[q];
      __syncthreads();
      #pragma unroll
      for (int cc=0; cc<2; ++cc){
        int col = tid*2+cc;
        float sum = 0.f;
        #pragma unroll
        for (int w2=0; w2<4; ++w2) sum += rr[(((size_t)w2*64 + (col>>3))<<3) + (col&7)];
        splitstore(&A.wcth[(size_t)b*512+col], &A.wctl[(size_t)b*512+col], sum);
      }
    }
    gbar(A.flags, A.genp, ++bt);

    // S4: xc = relu(preC[s] + wctx @ Wch^T)   (128 x 304, pads stay 0)
    if (vwg < 38){
      int rb = vwg / 19, cb = vwg % 19;
      int row0 = rb*64, col0 = cb*16;
      v4f g = tile_xwT(A.wcth, A.wctl, 512, 16, A.Wchh, A.Wchl, 512, row0, col0, red);
      const float* pre = A.preC + (size_t)s*128*320;
      int w = tid>>6, lane = tid&63;
      int col = col0 + (lane&15), rowb = row0 + w*16 + ((lane>>4)<<2);
      #pragma unroll
      for (int e=0;e<4;e++){
        int row = rowb+e;
        float v = (col<300)? fmaxf(g[e] + pre[(size_t)row*320+col], 0.f) : 0.f;
        splitstore(&A.xch[(size_t)row*320+col], &A.xcl[(size_t)row*320+col], v);
      }
    }
    gbar(A.flags, A.genp, ++bt);

    // S5: GRU layer 0: h0' = gru(xc, h0)  (Whh-L0 pinned; WGs 0-63)
    if (vwg < 64){
      int rb = vwg >> 5, cb = vwg & 31;
      int row0 = rb*64, col0 = cb*16;
      v4f gate[4];
      gru_tile_pin(A.xch, A.xcl, 320, 10, h0ph, h0pl,
                   A.dWih0h, A.dWih0l, 320, WL.wI, WL.wH, row0, col0, red, gate);
      gru_combine(gate, A.dbih, A.dbhh, h0ph, h0pl, h0nh, h0nl, row0, col0);
    }
    gbar(A.flags, A.genp, ++bt);

    // S6: GRU layer 1: h1' = gru(h0', h1)  (Whh-L1 pinned; WGs 64-127)
    if (vwg >= 64){
      int v2 = vwg - 64;
      int rb = v2 >> 5, cb = v2 & 31;
      int row0 = rb*64, col0 = cb*16;
      v4f gate[4];
      gru_tile_pin(h0nh, h0nl, 512, 16, h1ph, h1pl,
                   A.dWih1h, A.dWih1l, 512, WL.wI, WL.wH, row0, col0, red, gate);
      gru_combine(gate, A.dbih + 1536, A.dbhh + 1536, h1ph, h1pl, h1nh, h1nl, row0, col0);
    }
    gbar(A.flags, A.genp, ++bt);

    // S8': dec_out[:,s,:] = h1' @ W'^T + b'   (fused S7+S8; no trailing bar)
    if (vwg < 38){
      int rb = vwg / 19, cb = vwg % 19;
      int row0 = rb*64, col0 = cb*16;
      v4f g = tile_xwT(h1nh, h1nl, 512, 16, A.Wph, A.Wpl, 512, row0, col0, red);
      int w = tid>>6, lane = tid&63;
      int col = col0 + (lane&15), rowb = row0 + w*16 + ((lane>>4)<<2);
      #pragma unroll
      for (int e=0;e<4;e++){
        int row = rowb+e;
        if (col < 300) A.out[DECOUT_OFF + ((size_t)row*32 + s)*300 + col] = g[e] + A.bpr[col];
      }
    }
  }

  // ================= dec_hidden output (final h in buffer 0) ===============
  for (size_t i=gtid; i<65536; i+=P){
    A.out[DECHID_OFF + i]         = bf2f(A.dh0h[i]) + bf2f(A.dh0l[i]);
    A.out[DECHID_OFF + 65536 + i] = bf2f(A.dh1h[i]) + bf2f(A.dh1l[i]);
  }
}

// ===========================================================================
extern "C" void kernel_launch(void* const* d_in, const int* in_sizes, int n_in,
                              void* d_out, int out_size, void* d_ws, size_t ws_size,
                              hipStream_t stream){
  (void)in_sizes; (void)n_in; (void)out_size; (void)ws_size;
  KArgs A;
  A.x       = (const float*)d_in[0];  A.target = (const float*)d_in[1];
  A.eWih_f  = (const float*)d_in[2];  A.eWhh_f = (const float*)d_in[3];
  A.ebih    = (const float*)d_in[4];  A.ebhh   = (const float*)d_in[5];
  A.dWih0_f = (const float*)d_in[6];  A.dWih1_f= (const float*)d_in[7];
  A.dWhh_f  = (const float*)d_in[8];  A.dbih   = (const float*)d_in[9];
  A.dbhh    = (const float*)d_in[10];
  A.aWw_f   = (const float*)d_in[11]; A.aWb    = (const float*)d_in[12];
  A.aCw_f   = (const float*)d_in[13]; A.aCb    = (const float*)d_in[14];
  A.o1w_f   = (const float*)d_in[15]; A.o1b    = (const float*)d_in[16];
  A.o2w_f   = (const float*)d_in[17]; A.o2b    = (const float*)d_in[18];
  A.out = (float*)d_out;

  char* w = (char*)d_ws;
  size_t off = 0;
  auto alloc = [&](size_t bytes)->char*{
    char* p = w + off; off += (bytes + 255) & ~(size_t)255; return p;
  };
  char* barp = alloc(4096);
  A.flags  = (u32*)barp;               // [0..127]
  A.genp   = (u32*)(barp + 2048);
  A.ecnt   = (u32*)(barp + 2304);      // 8 u32 election counters
  A.xhi    = (u16*)alloc(128UL*256*512*2);
  A.h0hi   = (u16*)alloc(257UL*128*512*2);
  A.h1hi   = (u16*)alloc(2UL*128*512*2);
  A.encout = A.xhi;   // alias: layer0 reads xhi[t=k] while layer1 writes
                      // encout[t=k-1] -- trailing by one t-slice, disjoint
  A.dWih0h = (u16*)alloc(1536UL*320*2); A.dWih0l = (u16*)alloc(1536UL*320*2);
  A.dWih1h = (u16*)alloc(1536UL*512*2); A.dWih1l = (u16*)alloc(1536UL*512*2);
  A.dWhhh  = (u16*)alloc(2UL*1536*512*2); A.dWhhl = (u16*)alloc(2UL*1536*512*2);
  A.Wwhh   = (u16*)alloc(256UL*512*2);  A.Wwhl   = (u16*)alloc(256UL*512*2);
  A.Wwxh   = (u16*)alloc(256UL*320*2);  A.Wwxl   = (u16*)alloc(256UL*320*2);
  A.Wchh   = (u16*)alloc(304UL*512*2);  A.Wchl   = (u16*)alloc(304UL*512*2);
  A.Wcxh   = (u16*)alloc(304UL*320*2);  A.Wcxl   = (u16*)alloc(304UL*320*2);
  A.o2wh   = (u16*)alloc(320UL*320*2);  A.o2wl   = (u16*)alloc(320UL*320*2);
  A.o1Th   = (u16*)alloc(512UL*320*2);  A.o1Tl   = (u16*)alloc(512UL*320*2);
  A.Wph    = (u16*)alloc(304UL*512*2);  A.Wpl    = (u16*)alloc(304UL*512*2);
  A.bpr    = (float*)alloc(304UL*4);
  A.xth    = (u16*)alloc(32UL*128*320*2); A.xtl  = (u16*)alloc(32UL*128*320*2);
  A.preW   = (float*)alloc(32UL*128*256*4);
  A.preC   = (float*)alloc(32UL*128*320*4);
  A.dh0h   = (u16*)alloc(2UL*65536*2); A.dh0l = (u16*)alloc(2UL*65536*2);
  A.dh1h   = (u16*)alloc(2UL*65536*2); A.dh1l = (u16*)alloc(2UL*65536*2);
  A.logits = (float*)alloc(128UL*256*4);
  A.wcth   = (u16*)alloc(128UL*512*2); A.wctl = (u16*)alloc(128UL*512*2);
  A.xch    = (u16*)alloc(128UL*320*2); A.xcl  = (u16*)alloc(128UL*320*2);

  hipMemsetAsync(d_ws, 0, 4096, stream);   // reset barrier/election page each launch
  traffic_kernel<<<dim3(NWG), dim3(TPB), 0, stream>>>(A);
}